// Round 11
// baseline (778.257 us; speedup 1.0000x reference)
//
#include <hip/hip_runtime.h>
#include <hip/hip_bf16.h>
#include <stdint.h>

// ---------- helpers ----------
typedef __attribute__((ext_vector_type(8))) short short8v;    // 8 x bf16 bits (4 VGPRs)
typedef __attribute__((ext_vector_type(4))) float f32x4;
typedef __attribute__((ext_vector_type(16))) float f32x16;    // 32x32 acc

__device__ __forceinline__ unsigned short f2bf(float f) {
  unsigned u = __builtin_bit_cast(unsigned, f);
  unsigned r = 0x7fffu + ((u >> 16) & 1u);          // round-to-nearest-even
  return (unsigned short)((u + r) >> 16);
}
__device__ __forceinline__ float bf2f(unsigned short h) {
  unsigned u = ((unsigned)h) << 16;
  return __builtin_bit_cast(float, u);
}
__device__ __forceinline__ void gload_lds16(const void* g, void* l) {
  __builtin_amdgcn_global_load_lds(
      (const __attribute__((address_space(1))) void*)g,
      (__attribute__((address_space(3))) void*)l, 16, 0, 0);
}
// Inverse of the "r9-pattern" 32x32 LDS layout: phys granule p -> source
// element offset (r*K + g*8) within a 256x32 panel.
//   layout: el(r,g) = (r>>5)*1024 + (g>>1)*512 + (r&15)*32 + j*8,
//           j = (((r>>4)&1)|((g&1)<<1)) ^ ((r>>1)&3)          [bijective]
__device__ __forceinline__ unsigned src_off(int p, int K) {
  const int q = p & 63;
  const int u = (q & 3) ^ ((q >> 3) & 3);
  const int r = ((p >> 7) << 5) | ((u & 1) << 4) | (q >> 2);
  const int g = (((p >> 6) & 1) << 1) | (u >> 1);
  return (unsigned)r * (unsigned)K + (unsigned)(g * 8);
}
#define SBAR  __builtin_amdgcn_s_barrier()
#define SCHED __builtin_amdgcn_sched_barrier(0)

// ---------- split kernels ----------
__global__ __launch_bounds__(256) void split_plain(
    const float4* __restrict__ X, ushort4* __restrict__ H, ushort4* __restrict__ L, int n4) {
  int idx = blockIdx.x * 256 + threadIdx.x;
  if (idx >= n4) return;
  float4 v = X[idx];
  ushort4 h, l;
  h.x = f2bf(v.x); l.x = f2bf(v.x - bf2f(h.x));
  h.y = f2bf(v.y); l.y = f2bf(v.y - bf2f(h.y));
  h.z = f2bf(v.z); l.z = f2bf(v.z - bf2f(h.z));
  h.w = f2bf(v.w); l.w = f2bf(v.w - bf2f(h.w));
  H[idx] = h; L[idx] = l;
}

__global__ __launch_bounds__(256) void split_T(
    const float* __restrict__ W, unsigned short* __restrict__ H,
    unsigned short* __restrict__ L, int Kd, int Nd) {
  __shared__ float tile[32][33];
  const int t = threadIdx.x;
  const int c = t & 31;
  const int r0 = t >> 5;
  const int k0 = blockIdx.y * 32, n0 = blockIdx.x * 32;
#pragma unroll
  for (int i = 0; i < 4; ++i) {
    int r = r0 + i * 8;
    tile[r][c] = W[(size_t)(k0 + r) * Nd + n0 + c];
  }
  __syncthreads();
#pragma unroll
  for (int i = 0; i < 4; ++i) {
    int n = r0 + i * 8;
    float f = tile[c][n];
    unsigned short h = f2bf(f);
    unsigned short l = f2bf(f - bf2f(h));
    size_t o = (size_t)(n0 + n) * Kd + k0 + c;
    H[o] = h; L[o] = l;
  }
}

// ---------- FUSED split GEMM (32x32x16): C = Ah@Bl^T + Ah@Bh^T + Al@Bh^T ----------
// Sync skeleton/vmcnt/dest addressing: byte-identical to r8/r9 (tripwire-proven).
// r11 change vs r10: LDS layout re-derived so every 32x32 frag read has the
// EXACT per-lane byte-address pattern of r9's measured-conflict-free reads
// (BASE + (l&15)*64B + (((l>>4)^((l>>1)&3))&3)*16B). Staging keeps lane-linear
// dest; global SOURCE is the layout inverse (src_off). EPI 0: fp32; 2: hi/lo.
template<int EPI>
__global__ __launch_bounds__(512, 1) void gemm_fused3(
    const unsigned short* __restrict__ base,            // = Ah
    unsigned dAl, unsigned dBh, unsigned dBl,           // element offsets
    int N, int K,
    float* __restrict__ Cf, unsigned short* __restrict__ Ch, unsigned short* __restrict__ Cl) {
  __shared__ unsigned short lds[65536];   // 2 slots x [Ah|Bh|Bl|Al] x 8192 ush
  const int AH = 0, BH = 8192, BL = 16384, AL = 24576;
  const int NT = K >> 5;
  const int wg = blockIdx.x;
  const int sw = ((wg & 7) << 5) | (wg >> 3);     // XCD-bijective (256 wg)
  const int bx = sw & 15, by = sw >> 4;
  const int m0 = by << 8, n0 = bx << 8;

  const int tid = threadIdx.x;
  const int w = tid >> 6, lane = tid & 63;
  const int wr = w >> 2, wc = w & 3;               // wave tile 128x64
  // r9-pattern read offset (elements) within a 512-el set
  const int rdpat = (lane & 15) * 32 + ((((lane >> 4) ^ (lane >> 1)) & 3) << 3);
  // staging source offsets (per-lane), panel-relative
  const unsigned e1 = src_off(tid, K);
  const unsigned e2 = src_off(512 + tid, K);
  const unsigned voffA = (unsigned)m0 * (unsigned)K;   // wave-uniform
  const unsigned voffB = (unsigned)n0 * (unsigned)K;

  f32x16 acc[4][2];
#pragma unroll
  for (int m = 0; m < 4; ++m)
#pragma unroll
    for (int n = 0; n < 2; ++n)
#pragma unroll
      for (int r = 0; r < 16; ++r) acc[m][n][r] = 0.f;

#define STG2(dsel, vo, loff, s, tt) do {                                       \
    const unsigned b_ = (vo) + (dsel) + (unsigned)(tt) * 32u;                  \
    gload_lds16(base + b_ + e1, &lds[(s) + (loff) + (w << 9)]);                \
    gload_lds16(base + b_ + e2, &lds[(s) + (loff) + 4096 + (w << 9)]);         \
  } while (0)

  // prologue: stage tile 0 into slot 0, FIFO order [Ah, Bl, Bh, Al]  (8 ops)
  STG2(0u,  voffA, AH, 0, 0);
  STG2(dBl, voffB, BL, 0, 0);
  STG2(dBh, voffB, BH, 0, 0);
  STG2(dAl, voffA, AL, 0, 0);

  for (int t = 0; t < NT; ++t) {
    const int slot = (t & 1) << 15;
    const int slot1 = ((t + 1) & 1) << 15;
    const bool st = (t + 1) < NT;
    short8v ah[8];                            // [ks*4+m], live blocks 1-2
    // ---- block1 (h,l): certify Ah(t),Bl(t); outstanding 8 -> vmcnt(4) ----
    SCHED; asm volatile("s_waitcnt vmcnt(4)"); SBAR; SCHED;
    {
      short8v bl[4];                          // [ks*2+n]
#pragma unroll
      for (int ks = 0; ks < 2; ++ks) {
#pragma unroll
        for (int n = 0; n < 2; ++n)
          bl[ks * 2 + n] = *(const short8v*)&lds[slot + BL + (wc * 2 + n) * 1024 + ks * 512 + rdpat];
#pragma unroll
        for (int m = 0; m < 4; ++m)
          ah[ks * 4 + m] = *(const short8v*)&lds[slot + AH + (wr * 4 + m) * 1024 + ks * 512 + rdpat];
      }
      if (st) { STG2(0u, voffA, AH, slot1, t + 1); STG2(dBl, voffB, BL, slot1, t + 1); }
      __builtin_amdgcn_s_setprio(1);
#pragma unroll
      for (int ks = 0; ks < 2; ++ks)
#pragma unroll
        for (int m = 0; m < 4; ++m)
#pragma unroll
          for (int n = 0; n < 2; ++n)
            acc[m][n] = __builtin_amdgcn_mfma_f32_32x32x16_bf16(ah[ks * 4 + m], bl[ks * 2 + n], acc[m][n], 0, 0, 0);
      __builtin_amdgcn_s_setprio(0);
    }
    // ---- block2 (h,h): certify Bh(t); vmcnt(6) steady / (2) tail ----
    SCHED;
    if (st) { asm volatile("s_waitcnt vmcnt(6)"); }
    else    { asm volatile("s_waitcnt vmcnt(2)"); }
    SBAR; SCHED;
    short8v bh[4];                            // lives through block3
    {
#pragma unroll
      for (int ks = 0; ks < 2; ++ks)
#pragma unroll
        for (int n = 0; n < 2; ++n)
          bh[ks * 2 + n] = *(const short8v*)&lds[slot + BH + (wc * 2 + n) * 1024 + ks * 512 + rdpat];
      if (st) { STG2(dBh, voffB, BH, slot1, t + 1); }
      __builtin_amdgcn_s_setprio(1);
#pragma unroll
      for (int ks = 0; ks < 2; ++ks)
#pragma unroll
        for (int m = 0; m < 4; ++m)
#pragma unroll
          for (int n = 0; n < 2; ++n)
            acc[m][n] = __builtin_amdgcn_mfma_f32_32x32x16_bf16(ah[ks * 4 + m], bh[ks * 2 + n], acc[m][n], 0, 0, 0);
      __builtin_amdgcn_s_setprio(0);
    }
    // ah dies here
    // ---- block3 (l,h): certify Al(t); vmcnt(6) steady / (0) tail ----
    SCHED;
    if (st) { asm volatile("s_waitcnt vmcnt(6)"); }
    else    { asm volatile("s_waitcnt vmcnt(0)"); }
    SBAR; SCHED;
    {
      short8v al[8];
#pragma unroll
      for (int ks = 0; ks < 2; ++ks)
#pragma unroll
        for (int m = 0; m < 4; ++m)
          al[ks * 4 + m] = *(const short8v*)&lds[slot + AL + (wr * 4 + m) * 1024 + ks * 512 + rdpat];
      if (st) { STG2(dAl, voffA, AL, slot1, t + 1); }
      __builtin_amdgcn_s_setprio(1);
#pragma unroll
      for (int ks = 0; ks < 2; ++ks)
#pragma unroll
        for (int m = 0; m < 4; ++m)
#pragma unroll
          for (int n = 0; n < 2; ++n)
            acc[m][n] = __builtin_amdgcn_mfma_f32_32x32x16_bf16(al[ks * 4 + m], bh[ks * 2 + n], acc[m][n], 0, 0, 0);
      __builtin_amdgcn_s_setprio(0);
    }
    SCHED;
    // no end-of-tile barrier: block1's SBAR of tile t+1 separates the last
    // reads of slot (t-1)&1 from the next writes to it.
  }
#undef STG2

  // epilogue (32x32): col=lane&31, row=(reg&3)+8*(reg>>2)+4*(lane>>5)  [m74/m101]
  const int ccol = n0 + wc * 64 + (lane & 31);
  const int crow = m0 + wr * 128 + ((lane >> 5) << 2);
#pragma unroll
  for (int mi = 0; mi < 4; ++mi)
#pragma unroll
    for (int r = 0; r < 16; ++r) {
      const int row = crow + mi * 32 + (r & 3) + ((r >> 2) << 3);
#pragma unroll
      for (int n = 0; n < 2; ++n) {
        const int col = ccol + n * 32;
        const float f = acc[mi][n][r];
        const size_t o = (size_t)row * N + col;
        if (EPI == 0) {
          Cf[o] = f;
        } else {
          const unsigned short h = f2bf(f);
          Ch[o] = h;
          Cl[o] = f2bf(f - bf2f(h));
        }
      }
    }
}

// ---------- plain single-pass GEMM (32x32x16, r9-pattern layout): C = A @ B^T ----------
// 4-deep ring, counted vmcnt 8/4/0 before the barrier, one SBAR per tile
// (r2-proven skeleton). EPI 0: fp32; 1: bf16.
template<int EPI>
__global__ __launch_bounds__(512, 2) void gemm_plain(
    const unsigned short* __restrict__ A, const unsigned short* __restrict__ B,
    int N, int K,
    float* __restrict__ Cf, unsigned short* __restrict__ Ch) {
  __shared__ unsigned short lds[65536];   // 4 slots x (A 8192 + B 8192)
  const int NT = K >> 5;
  const int wg = blockIdx.x;
  const int sw = ((wg & 7) << 5) | (wg >> 3);
  const int bx = sw & 15, by = sw >> 4;
  const int m0 = by << 8, n0 = bx << 8;

  const int tid = threadIdx.x;
  const int w = tid >> 6, lane = tid & 63;
  const int wr = w >> 2, wc = w & 3;
  const int rdpat = (lane & 15) * 32 + ((((lane >> 4) ^ (lane >> 1)) & 3) << 3);
  const unsigned e1 = src_off(tid, K);
  const unsigned e2 = src_off(512 + tid, K);

  f32x16 acc[4][2];
#pragma unroll
  for (int m = 0; m < 4; ++m)
#pragma unroll
    for (int n = 0; n < 2; ++n)
#pragma unroll
      for (int r = 0; r < 16; ++r) acc[m][n][r] = 0.f;

  const unsigned short* gA = A + (size_t)m0 * K;
  const unsigned short* gB = B + (size_t)n0 * K;

  // prologue: stage tiles 0..2 into slots 0..2
#pragma unroll
  for (int tau = 0; tau < 3; ++tau) {
    const int so = tau * 16384 + (w << 9);
    const unsigned tb = (unsigned)tau * 32u;
    gload_lds16(gA + tb + e1, &lds[so]);
    gload_lds16(gA + tb + e2, &lds[so + 4096]);
    gload_lds16(gB + tb + e1, &lds[so + 8192]);
    gload_lds16(gB + tb + e2, &lds[so + 12288]);
  }
  asm volatile("s_waitcnt vmcnt(8)");
  SCHED; SBAR; SCHED;

  for (int t = 0; t < NT; ++t) {
    const int sb = (t & 3) * 16384;
    if (t + 3 < NT) {
      const int so = ((t + 3) & 3) * 16384 + (w << 9);
      const unsigned tb = (unsigned)(t + 3) * 32u;
      gload_lds16(gA + tb + e1, &lds[so]);
      gload_lds16(gA + tb + e2, &lds[so + 4096]);
      gload_lds16(gB + tb + e1, &lds[so + 8192]);
      gload_lds16(gB + tb + e2, &lds[so + 12288]);
    }
#pragma unroll
    for (int ks = 0; ks < 2; ++ks) {
      short8v bf[2], af[4];
#pragma unroll
      for (int n = 0; n < 2; ++n)
        bf[n] = *(const short8v*)&lds[sb + 8192 + (wc * 2 + n) * 1024 + ks * 512 + rdpat];
#pragma unroll
      for (int m = 0; m < 4; ++m)
        af[m] = *(const short8v*)&lds[sb + (wr * 4 + m) * 1024 + ks * 512 + rdpat];
      __builtin_amdgcn_s_setprio(1);
#pragma unroll
      for (int m = 0; m < 4; ++m)
#pragma unroll
        for (int n = 0; n < 2; ++n)
          acc[m][n] = __builtin_amdgcn_mfma_f32_32x32x16_bf16(af[m], bf[n], acc[m][n], 0, 0, 0);
      __builtin_amdgcn_s_setprio(0);
    }
    SCHED;
    if (t < NT - 3)       { asm volatile("s_waitcnt vmcnt(8)"); }
    else if (t == NT - 3) { asm volatile("s_waitcnt vmcnt(4)"); }
    else if (t == NT - 2) { asm volatile("s_waitcnt vmcnt(0)"); }
    SCHED;
    if (t < NT - 1) { SBAR; SCHED; }
  }

  const int ccol = n0 + wc * 64 + (lane & 31);
  const int crow = m0 + wr * 128 + ((lane >> 5) << 2);
#pragma unroll
  for (int mi = 0; mi < 4; ++mi)
#pragma unroll
    for (int r = 0; r < 16; ++r) {
      const int row = crow + mi * 32 + (r & 3) + ((r >> 2) << 3);
#pragma unroll
      for (int n = 0; n < 2; ++n) {
        const int col = ccol + n * 32;
        const float f = acc[mi][n][r];
        const size_t o = (size_t)row * N + col;
        if (EPI == 0) Cf[o] = f;
        else          Ch[o] = f2bf(f);
      }
    }
}

// ---------- row softmax: fp32 (n per row) -> bf16 p ----------
__global__ __launch_bounds__(256) void softmax_rows(
    const float* __restrict__ S, unsigned short* __restrict__ P, int n) {
  const int row = blockIdx.x;
  const int t = threadIdx.x;
  const float4* src = (const float4*)(S + (size_t)row * n);
  float4 v[4];
  float mx = -3.0e38f;
#pragma unroll
  for (int i = 0; i < 4; ++i) {
    v[i] = src[i * 256 + t];
    mx = fmaxf(mx, fmaxf(fmaxf(v[i].x, v[i].y), fmaxf(v[i].z, v[i].w)));
  }
#pragma unroll
  for (int off = 32; off; off >>= 1) mx = fmaxf(mx, __shfl_xor(mx, off));
  __shared__ float redm[4], reds[4];
  const int wid = t >> 6, lane = t & 63;
  if (lane == 0) redm[wid] = mx;
  __syncthreads();
  mx = fmaxf(fmaxf(redm[0], redm[1]), fmaxf(redm[2], redm[3]));
  float sum = 0.f;
#pragma unroll
  for (int i = 0; i < 4; ++i) {
    v[i].x = __expf(v[i].x - mx);
    v[i].y = __expf(v[i].y - mx);
    v[i].z = __expf(v[i].z - mx);
    v[i].w = __expf(v[i].w - mx);
    sum += (v[i].x + v[i].y) + (v[i].z + v[i].w);
  }
#pragma unroll
  for (int off = 32; off; off >>= 1) sum += __shfl_xor(sum, off);
  if (lane == 0) reds[wid] = sum;
  __syncthreads();
  sum = (reds[0] + reds[1]) + (reds[2] + reds[3]);
  float inv = 1.0f / sum;
#pragma unroll
  for (int i = 0; i < 4; ++i) {
    ushort4 o;
    o.x = f2bf(v[i].x * inv);
    o.y = f2bf(v[i].y * inv);
    o.z = f2bf(v[i].z * inv);
    o.w = f2bf(v[i].w * inv);
    *(ushort4*)(P + (size_t)row * n + (size_t)(i * 256 + t) * 4) = o;
  }
}

// ---------- launch ----------
extern "C" void kernel_launch(void* const* d_in, const int* in_sizes, int n_in,
                              void* d_out, int out_size, void* d_ws, size_t ws_size,
                              hipStream_t stream) {
  (void)in_sizes; (void)n_in; (void)out_size; (void)ws_size;
  const float* x  = (const float*)d_in[0];
  const float* Wq = (const float*)d_in[1];
  const float* Wk = (const float*)d_in[2];
  const float* Wv = (const float*)d_in[3];
  const int N = 4096, D = 1024;
  const size_t MB = 1ull << 20;
  char* ws = (char*)d_ws;
  unsigned short* xh  = (unsigned short*)(ws + 0 * MB);     // 8 MB
  unsigned short* xl  = (unsigned short*)(ws + 8 * MB);     // 8 MB
  unsigned short* wqh = (unsigned short*)(ws + 16 * MB);    // 8 MB
  unsigned short* wql = (unsigned short*)(ws + 24 * MB);    // 8 MB
  unsigned short* wkh = (unsigned short*)(ws + 32 * MB);    // 8 MB
  unsigned short* wkl = (unsigned short*)(ws + 40 * MB);    // 8 MB
  unsigned short* wvh = (unsigned short*)(ws + 48 * MB);    // 8 MB
  unsigned short* wvl = (unsigned short*)(ws + 56 * MB);    // 8 MB (written, unused)
  unsigned short* qh  = (unsigned short*)(ws + 64 * MB);    // 32 MB
  unsigned short* ql  = (unsigned short*)(ws + 96 * MB);    // 32 MB
  unsigned short* kh  = (unsigned short*)(ws + 128 * MB);   // 32 MB
  unsigned short* kl  = (unsigned short*)(ws + 160 * MB);   // 32 MB
  unsigned short* vT  = (unsigned short*)(ws + 16 * MB);    // 32 MB, over wq/wk splits (dead)
  unsigned short* p   = (unsigned short*)(ws + 64 * MB);    // 32 MB, over qh (dead)
  float* score = (float*)d_out;
  float* out   = (float*)d_out;

  const unsigned MEL = (unsigned)(MB / 2);   // elements per MB

  // 1) splits
  split_plain<<<(N * D / 4 + 255) / 256, 256, 0, stream>>>(
      (const float4*)x, (ushort4*)xh, (ushort4*)xl, N * D / 4);
  dim3 gT(N / 32, D / 32);
  split_T<<<gT, 256, 0, stream>>>(Wq, wqh, wql, D, N);
  split_T<<<gT, 256, 0, stream>>>(Wk, wkh, wkl, D, N);
  split_T<<<gT, 256, 0, stream>>>(Wv, wvh, wvl, D, N);

  const int GG = (N / 256) * (N / 256);   // 256 workgroups
  // 2) q = x@Wq fused 3-product split -> hi/lo bf16
  gemm_fused3<2><<<GG, 512, 0, stream>>>(xh, 8 * MEL, 16 * MEL, 24 * MEL,
                                         N, D, nullptr, qh, ql);
  // 3) k = x@Wk
  gemm_fused3<2><<<GG, 512, 0, stream>>>(xh, 8 * MEL, 32 * MEL, 40 * MEL,
                                         N, D, nullptr, kh, kl);
  // 4) vT = (x@Wv)^T  (plain bf16, 1-pass)
  gemm_plain<1><<<GG, 512, 0, stream>>>(wvh, xh, N, D, nullptr, vT);
  // 5) score = q@k^T fused, K=4096 -> fp32 d_out
  gemm_fused3<0><<<GG, 512, 0, stream>>>(qh, 32 * MEL, 64 * MEL, 96 * MEL,
                                         N, N, score, nullptr, nullptr);
  // 6) p = softmax(score) -> bf16
  softmax_rows<<<N, 256, 0, stream>>>(score, p, N);
  // 7) out = p @ vT^T -> fp32 d_out
  gemm_plain<0><<<GG, 512, 0, stream>>>(p, vT, N, N, out, nullptr);
}

// Round 12
// 382.508 us; speedup vs baseline: 2.0346x; 2.0346x over previous
//
#include <hip/hip_runtime.h>
#include <hip/hip_bf16.h>
#include <stdint.h>

// ---------- helpers ----------
typedef __attribute__((ext_vector_type(8))) short short8v;   // 8 x bf16 bits (4 VGPRs)
typedef __attribute__((ext_vector_type(4))) float f32x4;

__device__ __forceinline__ unsigned short f2bf(float f) {
  unsigned u = __builtin_bit_cast(unsigned, f);
  unsigned r = 0x7fffu + ((u >> 16) & 1u);          // round-to-nearest-even
  return (unsigned short)((u + r) >> 16);
}
__device__ __forceinline__ float bf2f(unsigned short h) {
  unsigned u = ((unsigned)h) << 16;
  return __builtin_bit_cast(float, u);
}
__device__ __forceinline__ void gload_lds16(const void* g, void* l) {
  __builtin_amdgcn_global_load_lds(
      (const __attribute__((address_space(1))) void*)g,
      (__attribute__((address_space(3))) void*)l, 16, 0, 0);
}
#define SBAR  __builtin_amdgcn_s_barrier()
#define SCHED __builtin_amdgcn_sched_barrier(0)

// ---------- split kernels ----------
__global__ __launch_bounds__(256) void split_plain(
    const float4* __restrict__ X, ushort4* __restrict__ H, ushort4* __restrict__ L, int n4) {
  int idx = blockIdx.x * 256 + threadIdx.x;
  if (idx >= n4) return;
  float4 v = X[idx];
  ushort4 h, l;
  h.x = f2bf(v.x); l.x = f2bf(v.x - bf2f(h.x));
  h.y = f2bf(v.y); l.y = f2bf(v.y - bf2f(h.y));
  h.z = f2bf(v.z); l.z = f2bf(v.z - bf2f(h.z));
  h.w = f2bf(v.w); l.w = f2bf(v.w - bf2f(h.w));
  H[idx] = h; L[idx] = l;
}

__global__ __launch_bounds__(256) void split_T(
    const float* __restrict__ W, unsigned short* __restrict__ H,
    unsigned short* __restrict__ L, int Kd, int Nd) {
  __shared__ float tile[32][33];
  const int t = threadIdx.x;
  const int c = t & 31;
  const int r0 = t >> 5;
  const int k0 = blockIdx.y * 32, n0 = blockIdx.x * 32;
#pragma unroll
  for (int i = 0; i < 4; ++i) {
    int r = r0 + i * 8;
    tile[r][c] = W[(size_t)(k0 + r) * Nd + n0 + c];
  }
  __syncthreads();
#pragma unroll
  for (int i = 0; i < 4; ++i) {
    int n = r0 + i * 8;
    float f = tile[c][n];
    unsigned short h = f2bf(f);
    unsigned short l = f2bf(f - bf2f(h));
    size_t o = (size_t)(n0 + n) * Kd + k0 + c;
    H[o] = h; L[o] = l;
  }
}

// ---------- M-transpose reduce: Mt[b][a] = split(sum_s Mpart[s][a][b]) ----------
__global__ __launch_bounds__(256) void reduceT_M(
    const float* __restrict__ P, unsigned short* __restrict__ H,
    unsigned short* __restrict__ L, int nsplit) {
  __shared__ float tile[32][33];
  const int t = threadIdx.x;
  const int c = t & 31;
  const int r0 = t >> 5;
  const int a0 = blockIdx.y * 32, b0 = blockIdx.x * 32;
#pragma unroll
  for (int i = 0; i < 4; ++i) {
    int r = r0 + i * 8;
    float s = 0.f;
    for (int sp = 0; sp < nsplit; ++sp)
      s += P[(size_t)sp * 1048576 + (size_t)(a0 + r) * 1024 + b0 + c];
    tile[r][c] = s;
  }
  __syncthreads();
#pragma unroll
  for (int i = 0; i < 4; ++i) {
    int b = r0 + i * 8;
    float f = tile[c][b];                 // = M[a0+c][b0+b]
    unsigned short h = f2bf(f);
    size_t o = (size_t)(b0 + b) * 1024 + a0 + c;   // Mt[b][a]
    H[o] = h;
    L[o] = f2bf(f - bf2f(h));
  }
}

// ---------- y reduce+split: yh/yl = split(sum_s ypart[s]) ----------
__global__ __launch_bounds__(256) void reduce_split_y(
    const float4* __restrict__ P, ushort4* __restrict__ H, ushort4* __restrict__ L,
    int n4, int nsplit, int stride4) {
  int idx = blockIdx.x * 256 + threadIdx.x;
  if (idx >= n4) return;
  float4 s = P[idx];
  for (int sp = 1; sp < nsplit; ++sp) {
    float4 v = P[(size_t)sp * stride4 + idx];
    s.x += v.x; s.y += v.y; s.z += v.z; s.w += v.w;
  }
  ushort4 h, l;
  h.x = f2bf(s.x); l.x = f2bf(s.x - bf2f(h.x));
  h.y = f2bf(s.y); l.y = f2bf(s.y - bf2f(h.y));
  h.z = f2bf(s.z); l.z = f2bf(s.z - bf2f(h.z));
  h.w = f2bf(s.w); l.w = f2bf(s.w - bf2f(h.w));
  H[idx] = h; L[idx] = l;
}

// ---------- FUSED split GEMM (r9-proven body): C = Ah@Bl^T + Ah@Bh^T + Al@Bh^T ----------
// One base pointer + uniform element offsets. 256x256 tile, BK=32, 2-slot ring.
// Sync skeleton tripwire-proven (r6-r9): each sub-block {vmcnt(N); SBAR; reads;
// stage(t+1); MFMA}; stage FIFO [Ah,Bl,Bh,Al]; vmcnt 4/6/6 steady, 4/2/0 tail.
// r12 additions (no sync change): dAh offset, K-split via blockIdx.y (koff,
// partStride), tilesX mapping when !SWZ. fp32 C only.
template<bool SWZ>
__global__ __launch_bounds__(512, 1) void gemm_fused3(
    const unsigned short* __restrict__ base,
    unsigned dAh, unsigned dAl, unsigned dBh, unsigned dBl,
    int N, int K, int kchunk, int tilesX,
    float* __restrict__ Cf, size_t partStride) {
  __shared__ unsigned short lds[65536];   // 2 slots x [Ah|Bh|Bl|Al] x 8192 ush
  const int AH = 0, BH = 8192, BL = 16384, AL = 24576;
  const int NT = kchunk >> 5;
  const int wg = blockIdx.x;
  int bx, by;
  if (SWZ) { const int sw = ((wg & 7) << 5) | (wg >> 3); bx = sw & 15; by = sw >> 4; }
  else     { bx = wg % tilesX; by = wg / tilesX; }
  const int m0 = by << 8, n0 = bx << 8;
  const unsigned koff = (unsigned)blockIdx.y * (unsigned)kchunk;
  Cf += (size_t)blockIdx.y * partStride;

  const int tid = threadIdx.x;
  const int w = tid >> 6, lane = tid & 63;
  const int wr = w >> 2, wc = w & 3;               // wave tile 128x64
  const int lr = lane & 15;
  const int phys = (lane >> 4) ^ ((lr >> 1) & 3);  // read-side swizzle
  const int aoff = (wr * 128 + lr) * 32 + phys * 8;   // + m*512
  const int boff = (wc * 64 + lr) * 32 + phys * 8;    // + n*512
  const int rst = tid >> 2;                            // staging source row
  const int ssrc = ((tid & 3) ^ ((tid >> 3) & 3)) * 8; // inverse-swizzled k-slot
  const unsigned jstep = 128u * (unsigned)K;

  const unsigned voffA = (unsigned)(m0 + rst) * (unsigned)K + (unsigned)ssrc + koff;
  const unsigned voffB = (unsigned)(n0 + rst) * (unsigned)K + (unsigned)ssrc + koff;

  f32x4 acc[8][4];
#pragma unroll
  for (int m = 0; m < 8; ++m)
#pragma unroll
    for (int n = 0; n < 4; ++n) acc[m][n] = {0.f, 0.f, 0.f, 0.f};

#define STG2(dsel, vo, loff, s, tt) do {                                     \
    const unsigned o_ = (vo) + (dsel) + (unsigned)(tt) * 32u;                \
    gload_lds16(base + o_,         &lds[(s) + (loff) + (w << 9)]);           \
    gload_lds16(base + o_ + jstep, &lds[(s) + (loff) + 4096 + (w << 9)]);    \
  } while (0)

  // prologue: stage tile 0 into slot 0, FIFO order [Ah, Bl, Bh, Al]  (8 ops)
  STG2(dAh, voffA, AH, 0, 0);
  STG2(dBl, voffB, BL, 0, 0);
  STG2(dBh, voffB, BH, 0, 0);
  STG2(dAl, voffA, AL, 0, 0);

  for (int t = 0; t < NT; ++t) {
    const int slot = (t & 1) << 15;
    const int slot1 = ((t + 1) & 1) << 15;
    const bool st = (t + 1) < NT;
    short8v ahf[8];                          // live across blocks 1-2
    // ---- block1 (h,l): certify Ah(t),Bl(t); outstanding 8 -> vmcnt(4) ----
    SCHED; asm volatile("s_waitcnt vmcnt(4)"); SBAR; SCHED;
    {
      short8v bf[4];
#pragma unroll
      for (int n = 0; n < 4; ++n)
        bf[n] = *(const short8v*)&lds[slot + BL + boff + n * 512];
#pragma unroll
      for (int m = 0; m < 8; ++m)
        ahf[m] = *(const short8v*)&lds[slot + AH + aoff + m * 512];
      if (st) { STG2(dAh, voffA, AH, slot1, t + 1); STG2(dBl, voffB, BL, slot1, t + 1); }
      __builtin_amdgcn_s_setprio(1);
#pragma unroll
      for (int m = 0; m < 8; ++m)
#pragma unroll
        for (int n = 0; n < 4; ++n)
          acc[m][n] = __builtin_amdgcn_mfma_f32_16x16x32_bf16(ahf[m], bf[n], acc[m][n], 0, 0, 0);
      __builtin_amdgcn_s_setprio(0);
    }
    // ---- block2 (h,h): certify Bh(t); vmcnt(6) steady / (2) tail ----
    SCHED;
    if (st) { asm volatile("s_waitcnt vmcnt(6)"); }
    else    { asm volatile("s_waitcnt vmcnt(2)"); }
    SBAR; SCHED;
    short8v bh[4];                           // lives through block3
    {
#pragma unroll
      for (int n = 0; n < 4; ++n)
        bh[n] = *(const short8v*)&lds[slot + BH + boff + n * 512];
      if (st) { STG2(dBh, voffB, BH, slot1, t + 1); }
      __builtin_amdgcn_s_setprio(1);
#pragma unroll
      for (int m = 0; m < 8; ++m)
#pragma unroll
        for (int n = 0; n < 4; ++n)
          acc[m][n] = __builtin_amdgcn_mfma_f32_16x16x32_bf16(ahf[m], bh[n], acc[m][n], 0, 0, 0);
      __builtin_amdgcn_s_setprio(0);
    }
    // ahf dies here
    // ---- block3 (l,h): certify Al(t); vmcnt(6) steady / (0) tail ----
    SCHED;
    if (st) { asm volatile("s_waitcnt vmcnt(6)"); }
    else    { asm volatile("s_waitcnt vmcnt(0)"); }
    SBAR; SCHED;
    {
      short8v alf[8];
#pragma unroll
      for (int m = 0; m < 8; ++m)
        alf[m] = *(const short8v*)&lds[slot + AL + aoff + m * 512];
      if (st) { STG2(dAl, voffA, AL, slot1, t + 1); }
      __builtin_amdgcn_s_setprio(1);
#pragma unroll
      for (int m = 0; m < 8; ++m)
#pragma unroll
        for (int n = 0; n < 4; ++n)
          acc[m][n] = __builtin_amdgcn_mfma_f32_16x16x32_bf16(alf[m], bh[n], acc[m][n], 0, 0, 0);
      __builtin_amdgcn_s_setprio(0);
    }
    SCHED;
    // no end-of-tile barrier: block1's SBAR of tile t+1 separates the last
    // reads of slot (t-1)&1 from the next writes to it.
  }
#undef STG2

  // epilogue: frag r -> row=(lane>>4)*4+r, col=lane&15  [m89/m91-verified]
  const int crow = m0 + wr * 128 + ((lane >> 4) << 2);
  const int ccol = n0 + wc * 64 + lr;
#pragma unroll
  for (int mi = 0; mi < 8; ++mi)
#pragma unroll
    for (int r = 0; r < 4; ++r) {
      const int row = crow + mi * 16 + r;
#pragma unroll
      for (int n = 0; n < 4; ++n)
        Cf[(size_t)row * N + ccol + n * 16] = acc[mi][n][r];
    }
}

// ---------- plain single-pass GEMM (r9-proven): C = A @ B^T ----------
// 4-deep ring, counted vmcnt 8/4/0 before the barrier, one SBAR per tile.
// EPI 0: fp32; 1: bf16.
template<int EPI>
__global__ __launch_bounds__(512, 2) void gemm_plain(
    const unsigned short* __restrict__ A, const unsigned short* __restrict__ B,
    int N, int K,
    float* __restrict__ Cf, unsigned short* __restrict__ Ch) {
  __shared__ unsigned short lds[65536];   // 4 slots x (A 8192 + B 8192)
  const int NT = K >> 5;
  const int wg = blockIdx.x;
  const int sw = ((wg & 7) << 5) | (wg >> 3);
  const int bx = sw & 15, by = sw >> 4;
  const int m0 = by << 8, n0 = bx << 8;

  const int tid = threadIdx.x;
  const int w = tid >> 6, lane = tid & 63;
  const int wr = w >> 2, wc = w & 3;
  const int lr = lane & 15;
  const int phys = (lane >> 4) ^ ((lr >> 1) & 3);
  const int aoff = (wr * 128 + lr) * 32 + phys * 8;
  const int boff = 8192 + (wc * 64 + lr) * 32 + phys * 8;
  const int rst = w * 16 + (lane >> 2);
  const int ssrc = ((lane & 3) ^ ((lane >> 3) & 3)) * 8;

  f32x4 acc[8][4];
#pragma unroll
  for (int m = 0; m < 8; ++m)
#pragma unroll
    for (int n = 0; n < 4; ++n) acc[m][n] = {0.f, 0.f, 0.f, 0.f};

  const unsigned short* gA = A + (size_t)(m0 + rst) * K + ssrc;
  const unsigned short* gB = B + (size_t)(n0 + rst) * K + ssrc;
  const size_t jstep = (size_t)128 * K;

  // prologue: stage tiles 0..2 into slots 0..2
#pragma unroll
  for (int tau = 0; tau < 3; ++tau) {
    const int so = tau * 16384 + (w << 9);
    gload_lds16(gA + (size_t)tau * 32, &lds[so]);
    gload_lds16(gA + (size_t)tau * 32 + jstep, &lds[so + 4096]);
    gload_lds16(gB + (size_t)tau * 32, &lds[so + 8192]);
    gload_lds16(gB + (size_t)tau * 32 + jstep, &lds[so + 12288]);
  }
  asm volatile("s_waitcnt vmcnt(8)");
  SCHED; SBAR; SCHED;

  for (int t = 0; t < NT; ++t) {
    const int sb = (t & 3) * 16384;
    if (t + 3 < NT) {
      const int so = ((t + 3) & 3) * 16384 + (w << 9);
      const unsigned short* srcA = gA + (size_t)(t + 3) * 32;
      const unsigned short* srcB = gB + (size_t)(t + 3) * 32;
      gload_lds16(srcA, &lds[so]);
      gload_lds16(srcA + jstep, &lds[so + 4096]);
      gload_lds16(srcB, &lds[so + 8192]);
      gload_lds16(srcB + jstep, &lds[so + 12288]);
    }
    short8v bfr[4], af0[4], af1[4];
#pragma unroll
    for (int n = 0; n < 4; ++n)
      bfr[n] = *(const short8v*)&lds[sb + boff + n * 512];
#pragma unroll
    for (int m = 0; m < 4; ++m)
      af0[m] = *(const short8v*)&lds[sb + aoff + m * 512];
#pragma unroll
    for (int m = 0; m < 4; ++m)
      af1[m] = *(const short8v*)&lds[sb + aoff + 2048 + m * 512];
    __builtin_amdgcn_s_setprio(1);
#pragma unroll
    for (int m = 0; m < 4; ++m)
#pragma unroll
      for (int n = 0; n < 4; ++n)
        acc[m][n] = __builtin_amdgcn_mfma_f32_16x16x32_bf16(af0[m], bfr[n], acc[m][n], 0, 0, 0);
#pragma unroll
    for (int m = 0; m < 4; ++m)
#pragma unroll
      for (int n = 0; n < 4; ++n)
        acc[4 + m][n] = __builtin_amdgcn_mfma_f32_16x16x32_bf16(af1[m], bfr[n], acc[4 + m][n], 0, 0, 0);
    __builtin_amdgcn_s_setprio(0);
    SCHED;
    if (t < NT - 3)       { asm volatile("s_waitcnt vmcnt(8)"); }
    else if (t == NT - 3) { asm volatile("s_waitcnt vmcnt(4)"); }
    else if (t == NT - 2) { asm volatile("s_waitcnt vmcnt(0)"); }
    SCHED;
    if (t < NT - 1) { SBAR; SCHED; }
  }

  const int crow = m0 + wr * 128 + ((lane >> 4) << 2);
  const int ccol = n0 + wc * 64 + lr;
#pragma unroll
  for (int mi = 0; mi < 8; ++mi)
#pragma unroll
    for (int r = 0; r < 4; ++r) {
      const int row = crow + mi * 16 + r;
#pragma unroll
      for (int n = 0; n < 4; ++n) {
        const int col = ccol + n * 16;
        const float f = acc[mi][n][r];
        const size_t o = (size_t)row * N + col;
        if (EPI == 0) Cf[o] = f;
        else          Ch[o] = f2bf(f);
      }
    }
}

// ---------- row softmax: fp32 (n per row) -> bf16 p ----------
__global__ __launch_bounds__(256) void softmax_rows(
    const float* __restrict__ S, unsigned short* __restrict__ P, int n) {
  const int row = blockIdx.x;
  const int t = threadIdx.x;
  const float4* src = (const float4*)(S + (size_t)row * n);
  float4 v[4];
  float mx = -3.0e38f;
#pragma unroll
  for (int i = 0; i < 4; ++i) {
    v[i] = src[i * 256 + t];
    mx = fmaxf(mx, fmaxf(fmaxf(v[i].x, v[i].y), fmaxf(v[i].z, v[i].w)));
  }
#pragma unroll
  for (int off = 32; off; off >>= 1) mx = fmaxf(mx, __shfl_xor(mx, off));
  __shared__ float redm[4], reds[4];
  const int wid = t >> 6, lane = t & 63;
  if (lane == 0) redm[wid] = mx;
  __syncthreads();
  mx = fmaxf(fmaxf(redm[0], redm[1]), fmaxf(redm[2], redm[3]));
  float sum = 0.f;
#pragma unroll
  for (int i = 0; i < 4; ++i) {
    v[i].x = __expf(v[i].x - mx);
    v[i].y = __expf(v[i].y - mx);
    v[i].z = __expf(v[i].z - mx);
    v[i].w = __expf(v[i].w - mx);
    sum += (v[i].x + v[i].y) + (v[i].z + v[i].w);
  }
#pragma unroll
  for (int off = 32; off; off >>= 1) sum += __shfl_xor(sum, off);
  if (lane == 0) reds[wid] = sum;
  __syncthreads();
  sum = (reds[0] + reds[1]) + (reds[2] + reds[3]);
  float inv = 1.0f / sum;
#pragma unroll
  for (int i = 0; i < 4; ++i) {
    ushort4 o;
    o.x = f2bf(v[i].x * inv);
    o.y = f2bf(v[i].y * inv);
    o.z = f2bf(v[i].z * inv);
    o.w = f2bf(v[i].w * inv);
    *(ushort4*)(P + (size_t)row * n + (size_t)(i * 256 + t) * 4) = o;
  }
}

// ---------- launch ----------
extern "C" void kernel_launch(void* const* d_in, const int* in_sizes, int n_in,
                              void* d_out, int out_size, void* d_ws, size_t ws_size,
                              hipStream_t stream) {
  (void)in_sizes; (void)n_in; (void)out_size; (void)ws_size;
  const float* x  = (const float*)d_in[0];
  const float* Wq = (const float*)d_in[1];
  const float* Wk = (const float*)d_in[2];
  const float* Wv = (const float*)d_in[3];
  const int N = 4096, D = 1024;
  const size_t MB = 1ull << 20;
  const unsigned MEL = (unsigned)(MB / 2);   // bf16 elements per MB
  char* ws = (char*)d_ws;
  // liveness-phased layout (peak 128 MB):
  unsigned short* xh  = (unsigned short*)(ws + 0 * MB);    // live all phases
  unsigned short* xl  = (unsigned short*)(ws + 8 * MB);
  unsigned short* wqh = (unsigned short*)(ws + 16 * MB);   // dead after M
  unsigned short* wql = (unsigned short*)(ws + 24 * MB);
  unsigned short* wkh = (unsigned short*)(ws + 32 * MB);
  unsigned short* wkl = (unsigned short*)(ws + 40 * MB);
  unsigned short* wvh = (unsigned short*)(ws + 48 * MB);   // live till vT gemm
  unsigned short* wvl = (unsigned short*)(ws + 56 * MB);   // dead immediately
  unsigned short* Mth = (unsigned short*)(ws + 56 * MB);   // over wvl (2 MB)
  unsigned short* Mtl = (unsigned short*)(ws + 58 * MB);   // 2 MB
  float*          Mpart = (float*)(ws + 64 * MB);          // 16 x 4 MB
  float*          ypart = (float*)(ws + 64 * MB);          // 4 x 16 MB (over Mpart)
  unsigned short* yh  = (unsigned short*)(ws + 16 * MB);   // over wqh (after M)
  unsigned short* yl  = (unsigned short*)(ws + 24 * MB);   // over wql
  unsigned short* vT  = (unsigned short*)(ws + 64 * MB);   // over ypart (after y)
  unsigned short* p   = (unsigned short*)(ws + 96 * MB);   // over ypart[2..3]
  float* score = (float*)d_out;
  float* out   = (float*)d_out;

  // 1) splits (plain, no transpose for Wq/Wk — M-GEMM consumes original layout)
  split_plain<<<4096, 256, 0, stream>>>((const float4*)x,  (ushort4*)xh,  (ushort4*)xl,  1048576);
  split_plain<<<4096, 256, 0, stream>>>((const float4*)Wq, (ushort4*)wqh, (ushort4*)wql, 1048576);
  split_plain<<<4096, 256, 0, stream>>>((const float4*)Wk, (ushort4*)wkh, (ushort4*)wkl, 1048576);
  split_T<<<dim3(N / 32, D / 32), 256, 0, stream>>>(Wv, wvh, wvl, D, N);

  // 2) M = Wq @ Wk^T (1024x1024, K=4096), 3-pass split, 16-way K-split
  //    grid (16 tiles [4x4], 16 chunks of K=256) = 256 wg
  gemm_fused3<false><<<dim3(16, 16), 512, 0, stream>>>(
      wqh, 0u, 8 * MEL, 16 * MEL, 24 * MEL,
      1024, 4096, 256, 4, Mpart, (size_t)1024 * 1024);
  // 3) Mt = transpose(sum Mpart) -> split hi/lo bf16
  reduceT_M<<<dim3(32, 32), 256, 0, stream>>>(Mpart, Mth, Mtl, 16);

  // 4) y = x @ M = x @ Mt^T (4096x1024, K=1024), 3-pass split, 4-way K-split
  //    grid (64 tiles [4x16], 4 chunks of K=256) = 256 wg
  gemm_fused3<false><<<dim3(64, 4), 512, 0, stream>>>(
      xh, 0u, 8 * MEL, 56 * MEL, 58 * MEL,
      1024, 1024, 256, 4, ypart, (size_t)4096 * 1024);
  // 5) yh/yl = split(sum ypart)
  reduce_split_y<<<4096, 256, 0, stream>>>(
      (const float4*)ypart, (ushort4*)yh, (ushort4*)yl, 1048576, 4, 1048576);

  // 6) vT = (x @ Wv)^T (plain bf16, K=1024) — after y so vT may overlay ypart
  gemm_plain<1><<<256, 512, 0, stream>>>(wvh, xh, N, D, nullptr, vT);

  // 7) score = y @ x^T (4096x4096, K=1024), 3-pass split -> fp32 d_out
  gemm_fused3<true><<<dim3(256, 1), 512, 0, stream>>>(
      xh, 16 * MEL, 24 * MEL, 0u, 8 * MEL,
      N, 1024, 1024, 16, score, 0);

  // 8) p = softmax(score) -> bf16
  softmax_rows<<<N, 256, 0, stream>>>(score, p, N);
  // 9) out = p @ vT^T -> fp32 d_out
  gemm_plain<0><<<256, 512, 0, stream>>>(p, vT, N, N, out, nullptr);
}

// Round 14
// 335.028 us; speedup vs baseline: 2.3230x; 1.1417x over previous
//
#include <hip/hip_runtime.h>
#include <hip/hip_bf16.h>
#include <stdint.h>

// ---------- helpers ----------
typedef __attribute__((ext_vector_type(8))) short short8v;   // 8 x bf16 bits (4 VGPRs)
typedef __attribute__((ext_vector_type(4))) float f32x4;

__device__ __forceinline__ unsigned short f2bf(float f) {
  unsigned u = __builtin_bit_cast(unsigned, f);
  unsigned r = 0x7fffu + ((u >> 16) & 1u);          // round-to-nearest-even
  return (unsigned short)((u + r) >> 16);
}
__device__ __forceinline__ float bf2f(unsigned short h) {
  unsigned u = ((unsigned)h) << 16;
  return __builtin_bit_cast(float, u);
}
__device__ __forceinline__ void gload_lds16(const void* g, void* l) {
  __builtin_amdgcn_global_load_lds(
      (const __attribute__((address_space(1))) void*)g,
      (__attribute__((address_space(3))) void*)l, 16, 0, 0);
}
#define SBAR  __builtin_amdgcn_s_barrier()
#define SCHED __builtin_amdgcn_sched_barrier(0)

// ---------- split kernels ----------
__global__ __launch_bounds__(256) void split_plain(
    const float4* __restrict__ X, ushort4* __restrict__ H, ushort4* __restrict__ L, int n4) {
  int idx = blockIdx.x * 256 + threadIdx.x;
  if (idx >= n4) return;
  float4 v = X[idx];
  ushort4 h, l;
  h.x = f2bf(v.x); l.x = f2bf(v.x - bf2f(h.x));
  h.y = f2bf(v.y); l.y = f2bf(v.y - bf2f(h.y));
  h.z = f2bf(v.z); l.z = f2bf(v.z - bf2f(h.z));
  h.w = f2bf(v.w); l.w = f2bf(v.w - bf2f(h.w));
  H[idx] = h; L[idx] = l;
}

__global__ __launch_bounds__(256) void split_T(
    const float* __restrict__ W, unsigned short* __restrict__ H,
    unsigned short* __restrict__ L, int Kd, int Nd) {
  __shared__ float tile[32][33];
  const int t = threadIdx.x;
  const int c = t & 31;
  const int r0 = t >> 5;
  const int k0 = blockIdx.y * 32, n0 = blockIdx.x * 32;
#pragma unroll
  for (int i = 0; i < 4; ++i) {
    int r = r0 + i * 8;
    tile[r][c] = W[(size_t)(k0 + r) * Nd + n0 + c];
  }
  __syncthreads();
#pragma unroll
  for (int i = 0; i < 4; ++i) {
    int n = r0 + i * 8;
    float f = tile[c][n];
    unsigned short h = f2bf(f);
    unsigned short l = f2bf(f - bf2f(h));
    size_t o = (size_t)(n0 + n) * Kd + k0 + c;
    H[o] = h; L[o] = l;
  }
}

// ---------- M-transpose reduce: Mt[b][a] = split(sum_s Mpart[s][a][b]) ----------
__global__ __launch_bounds__(256) void reduceT_M(
    const float* __restrict__ P, unsigned short* __restrict__ H,
    unsigned short* __restrict__ L, int nsplit) {
  __shared__ float tile[32][33];
  const int t = threadIdx.x;
  const int c = t & 31;
  const int r0 = t >> 5;
  const int a0 = blockIdx.y * 32, b0 = blockIdx.x * 32;
#pragma unroll
  for (int i = 0; i < 4; ++i) {
    int r = r0 + i * 8;
    float s = 0.f;
    for (int sp = 0; sp < nsplit; ++sp)
      s += P[(size_t)sp * 1048576 + (size_t)(a0 + r) * 1024 + b0 + c];
    tile[r][c] = s;
  }
  __syncthreads();
#pragma unroll
  for (int i = 0; i < 4; ++i) {
    int b = r0 + i * 8;
    float f = tile[c][b];                 // = M[a0+c][b0+b]
    unsigned short h = f2bf(f);
    size_t o = (size_t)(b0 + b) * 1024 + a0 + c;   // Mt[b][a]
    H[o] = h;
    L[o] = f2bf(f - bf2f(h));
  }
}

// ---------- reduce+split: H/L = split(sum_s P[s]) ----------
__global__ __launch_bounds__(256) void reduce_split(
    const float4* __restrict__ P, ushort4* __restrict__ H, ushort4* __restrict__ L,
    int n4, int nsplit, int stride4) {
  int idx = blockIdx.x * 256 + threadIdx.x;
  if (idx >= n4) return;
  float4 s = P[idx];
  for (int sp = 1; sp < nsplit; ++sp) {
    float4 v = P[(size_t)sp * stride4 + idx];
    s.x += v.x; s.y += v.y; s.z += v.z; s.w += v.w;
  }
  ushort4 h, l;
  h.x = f2bf(s.x); l.x = f2bf(s.x - bf2f(h.x));
  h.y = f2bf(s.y); l.y = f2bf(s.y - bf2f(h.y));
  h.z = f2bf(s.z); l.z = f2bf(s.z - bf2f(h.z));
  h.w = f2bf(s.w); l.w = f2bf(s.w - bf2f(h.w));
  H[idx] = h; L[idx] = l;
}

// ---------- FUSED split GEMM (r9-proven body): C = Ah@Bl^T + Ah@Bh^T + Al@Bh^T ----------
// One base pointer + uniform element offsets. 256x256 tile, BK=32, 2-slot ring.
// Sync skeleton tripwire-proven (r6-r12): each sub-block {vmcnt(N); SBAR; reads;
// stage(t+1); MFMA}; stage FIFO [Ah,Bl,Bh,Al]; vmcnt 4/6/6 steady, 4/2/0 tail.
// K-split via blockIdx.y (koff, partStride), tilesX mapping when !SWZ. fp32 C.
template<bool SWZ>
__global__ __launch_bounds__(512, 1) void gemm_fused3(
    const unsigned short* __restrict__ base,
    unsigned dAh, unsigned dAl, unsigned dBh, unsigned dBl,
    int N, int K, int kchunk, int tilesX,
    float* __restrict__ Cf, size_t partStride) {
  __shared__ unsigned short lds[65536];   // 2 slots x [Ah|Bh|Bl|Al] x 8192 ush
  const int AH = 0, BH = 8192, BL = 16384, AL = 24576;
  const int NT = kchunk >> 5;
  const int wg = blockIdx.x;
  int bx, by;
  if (SWZ) { const int sw = ((wg & 7) << 5) | (wg >> 3); bx = sw & 15; by = sw >> 4; }
  else     { bx = wg % tilesX; by = wg / tilesX; }
  const int m0 = by << 8, n0 = bx << 8;
  const unsigned koff = (unsigned)blockIdx.y * (unsigned)kchunk;
  Cf += (size_t)blockIdx.y * partStride;

  const int tid = threadIdx.x;
  const int w = tid >> 6, lane = tid & 63;
  const int wr = w >> 2, wc = w & 3;               // wave tile 128x64
  const int lr = lane & 15;
  const int phys = (lane >> 4) ^ ((lr >> 1) & 3);  // read-side swizzle
  const int aoff = (wr * 128 + lr) * 32 + phys * 8;   // + m*512
  const int boff = (wc * 64 + lr) * 32 + phys * 8;    // + n*512
  const int rst = tid >> 2;                            // staging source row
  const int ssrc = ((tid & 3) ^ ((tid >> 3) & 3)) * 8; // inverse-swizzled k-slot
  const unsigned jstep = 128u * (unsigned)K;

  const unsigned voffA = (unsigned)(m0 + rst) * (unsigned)K + (unsigned)ssrc + koff;
  const unsigned voffB = (unsigned)(n0 + rst) * (unsigned)K + (unsigned)ssrc + koff;

  f32x4 acc[8][4];
#pragma unroll
  for (int m = 0; m < 8; ++m)
#pragma unroll
    for (int n = 0; n < 4; ++n) acc[m][n] = {0.f, 0.f, 0.f, 0.f};

#define STG2(dsel, vo, loff, s, tt) do {                                     \
    const unsigned o_ = (vo) + (dsel) + (unsigned)(tt) * 32u;                \
    gload_lds16(base + o_,         &lds[(s) + (loff) + (w << 9)]);           \
    gload_lds16(base + o_ + jstep, &lds[(s) + (loff) + 4096 + (w << 9)]);    \
  } while (0)

  // prologue: stage tile 0 into slot 0, FIFO order [Ah, Bl, Bh, Al]  (8 ops)
  STG2(dAh, voffA, AH, 0, 0);
  STG2(dBl, voffB, BL, 0, 0);
  STG2(dBh, voffB, BH, 0, 0);
  STG2(dAl, voffA, AL, 0, 0);

  for (int t = 0; t < NT; ++t) {
    const int slot = (t & 1) << 15;
    const int slot1 = ((t + 1) & 1) << 15;
    const bool st = (t + 1) < NT;
    short8v ahf[8];                          // live across blocks 1-2
    // ---- block1 (h,l): certify Ah(t),Bl(t); outstanding 8 -> vmcnt(4) ----
    SCHED; asm volatile("s_waitcnt vmcnt(4)"); SBAR; SCHED;
    {
      short8v bf[4];
#pragma unroll
      for (int n = 0; n < 4; ++n)
        bf[n] = *(const short8v*)&lds[slot + BL + boff + n * 512];
#pragma unroll
      for (int m = 0; m < 8; ++m)
        ahf[m] = *(const short8v*)&lds[slot + AH + aoff + m * 512];
      if (st) { STG2(dAh, voffA, AH, slot1, t + 1); STG2(dBl, voffB, BL, slot1, t + 1); }
      __builtin_amdgcn_s_setprio(1);
#pragma unroll
      for (int m = 0; m < 8; ++m)
#pragma unroll
        for (int n = 0; n < 4; ++n)
          acc[m][n] = __builtin_amdgcn_mfma_f32_16x16x32_bf16(ahf[m], bf[n], acc[m][n], 0, 0, 0);
      __builtin_amdgcn_s_setprio(0);
    }
    // ---- block2 (h,h): certify Bh(t); vmcnt(6) steady / (2) tail ----
    SCHED;
    if (st) { asm volatile("s_waitcnt vmcnt(6)"); }
    else    { asm volatile("s_waitcnt vmcnt(2)"); }
    SBAR; SCHED;
    short8v bh[4];                           // lives through block3
    {
#pragma unroll
      for (int n = 0; n < 4; ++n)
        bh[n] = *(const short8v*)&lds[slot + BH + boff + n * 512];
      if (st) { STG2(dBh, voffB, BH, slot1, t + 1); }
      __builtin_amdgcn_s_setprio(1);
#pragma unroll
      for (int m = 0; m < 8; ++m)
#pragma unroll
        for (int n = 0; n < 4; ++n)
          acc[m][n] = __builtin_amdgcn_mfma_f32_16x16x32_bf16(ahf[m], bh[n], acc[m][n], 0, 0, 0);
      __builtin_amdgcn_s_setprio(0);
    }
    // ahf dies here
    // ---- block3 (l,h): certify Al(t); vmcnt(6) steady / (0) tail ----
    SCHED;
    if (st) { asm volatile("s_waitcnt vmcnt(6)"); }
    else    { asm volatile("s_waitcnt vmcnt(0)"); }
    SBAR; SCHED;
    {
      short8v alf[8];
#pragma unroll
      for (int m = 0; m < 8; ++m)
        alf[m] = *(const short8v*)&lds[slot + AL + aoff + m * 512];
      if (st) { STG2(dAl, voffA, AL, slot1, t + 1); }
      __builtin_amdgcn_s_setprio(1);
#pragma unroll
      for (int m = 0; m < 8; ++m)
#pragma unroll
        for (int n = 0; n < 4; ++n)
          acc[m][n] = __builtin_amdgcn_mfma_f32_16x16x32_bf16(alf[m], bh[n], acc[m][n], 0, 0, 0);
      __builtin_amdgcn_s_setprio(0);
    }
    SCHED;
    // no end-of-tile barrier: block1's SBAR of tile t+1 separates the last
    // reads of slot (t-1)&1 from the next writes to it.
  }
#undef STG2

  // epilogue: frag r -> row=(lane>>4)*4+r, col=lane&15  [m89/m91-verified]
  const int crow = m0 + wr * 128 + ((lane >> 4) << 2);
  const int ccol = n0 + wc * 64 + lr;
#pragma unroll
  for (int mi = 0; mi < 8; ++mi)
#pragma unroll
    for (int r = 0; r < 4; ++r) {
      const int row = crow + mi * 16 + r;
#pragma unroll
      for (int n = 0; n < 4; ++n)
        Cf[(size_t)row * N + ccol + n * 16] = acc[mi][n][r];
    }
}

// ---------- plain single-pass GEMM (r9-proven body): C = A @ B^T ----------
// 4-deep ring, counted vmcnt 8/4/0 before the barrier, one SBAR per tile.
// SWZ flag, K-split via blockIdx.y (kchunk, partStride), tilesX.
// EPI 0: fp32; 1: bf16.
template<int EPI, bool SWZ>
__global__ __launch_bounds__(512, 2) void gemm_plain(
    const unsigned short* __restrict__ A, const unsigned short* __restrict__ B,
    int N, int K, int kchunk, int tilesX,
    float* __restrict__ Cf, unsigned short* __restrict__ Ch, size_t partStride) {
  __shared__ unsigned short lds[65536];   // 4 slots x (A 8192 + B 8192)
  const int NT = kchunk >> 5;
  const int wg = blockIdx.x;
  int bx, by;
  if (SWZ) { const int sw = ((wg & 7) << 5) | (wg >> 3); bx = sw & 15; by = sw >> 4; }
  else     { bx = wg % tilesX; by = wg / tilesX; }
  const int m0 = by << 8, n0 = bx << 8;
  const unsigned koff = (unsigned)blockIdx.y * (unsigned)kchunk;
  Cf += (size_t)blockIdx.y * partStride;

  const int tid = threadIdx.x;
  const int w = tid >> 6, lane = tid & 63;
  const int wr = w >> 2, wc = w & 3;
  const int lr = lane & 15;
  const int phys = (lane >> 4) ^ ((lr >> 1) & 3);
  const int aoff = (wr * 128 + lr) * 32 + phys * 8;
  const int boff = 8192 + (wc * 64 + lr) * 32 + phys * 8;
  const int rst = w * 16 + (lane >> 2);
  const int ssrc = ((lane & 3) ^ ((lane >> 3) & 3)) * 8;

  f32x4 acc[8][4];
#pragma unroll
  for (int m = 0; m < 8; ++m)
#pragma unroll
    for (int n = 0; n < 4; ++n) acc[m][n] = {0.f, 0.f, 0.f, 0.f};

  const unsigned short* gA = A + (size_t)(m0 + rst) * K + ssrc + koff;
  const unsigned short* gB = B + (size_t)(n0 + rst) * K + ssrc + koff;
  const size_t jstep = (size_t)128 * K;

  // prologue: stage tiles 0..2 into slots 0..2
#pragma unroll
  for (int tau = 0; tau < 3; ++tau) {
    const int so = tau * 16384 + (w << 9);
    gload_lds16(gA + (size_t)tau * 32, &lds[so]);
    gload_lds16(gA + (size_t)tau * 32 + jstep, &lds[so + 4096]);
    gload_lds16(gB + (size_t)tau * 32, &lds[so + 8192]);
    gload_lds16(gB + (size_t)tau * 32 + jstep, &lds[so + 12288]);
  }
  asm volatile("s_waitcnt vmcnt(8)");
  SCHED; SBAR; SCHED;

  for (int t = 0; t < NT; ++t) {
    const int sb = (t & 3) * 16384;
    if (t + 3 < NT) {
      const int so = ((t + 3) & 3) * 16384 + (w << 9);
      const unsigned short* srcA = gA + (size_t)(t + 3) * 32;
      const unsigned short* srcB = gB + (size_t)(t + 3) * 32;
      gload_lds16(srcA, &lds[so]);
      gload_lds16(srcA + jstep, &lds[so + 4096]);
      gload_lds16(srcB, &lds[so + 8192]);
      gload_lds16(srcB + jstep, &lds[so + 12288]);
    }
    short8v bfr[4], af0[4], af1[4];
#pragma unroll
    for (int n = 0; n < 4; ++n)
      bfr[n] = *(const short8v*)&lds[sb + boff + n * 512];
#pragma unroll
    for (int m = 0; m < 4; ++m)
      af0[m] = *(const short8v*)&lds[sb + aoff + m * 512];
#pragma unroll
    for (int m = 0; m < 4; ++m)
      af1[m] = *(const short8v*)&lds[sb + aoff + 2048 + m * 512];
    __builtin_amdgcn_s_setprio(1);
#pragma unroll
    for (int m = 0; m < 4; ++m)
#pragma unroll
      for (int n = 0; n < 4; ++n)
        acc[m][n] = __builtin_amdgcn_mfma_f32_16x16x32_bf16(af0[m], bfr[n], acc[m][n], 0, 0, 0);
#pragma unroll
    for (int m = 0; m < 4; ++m)
#pragma unroll
      for (int n = 0; n < 4; ++n)
        acc[4 + m][n] = __builtin_amdgcn_mfma_f32_16x16x32_bf16(af1[m], bfr[n], acc[4 + m][n], 0, 0, 0);
    __builtin_amdgcn_s_setprio(0);
    SCHED;
    if (t < NT - 3)       { asm volatile("s_waitcnt vmcnt(8)"); }
    else if (t == NT - 3) { asm volatile("s_waitcnt vmcnt(4)"); }
    else if (t == NT - 2) { asm volatile("s_waitcnt vmcnt(0)"); }
    SCHED;
    if (t < NT - 1) { SBAR; SCHED; }
  }

  const int crow = m0 + wr * 128 + ((lane >> 4) << 2);
  const int ccol = n0 + wc * 64 + lr;
#pragma unroll
  for (int mi = 0; mi < 8; ++mi)
#pragma unroll
    for (int r = 0; r < 4; ++r) {
      const int row = crow + mi * 16 + r;
#pragma unroll
      for (int n = 0; n < 4; ++n) {
        const int col = ccol + n * 16;
        const float f = acc[mi][n][r];
        const size_t o = (size_t)row * N + col;
        if (EPI == 0) Cf[o] = f;
        else          Ch[o] = f2bf(f);
      }
    }
}

// ---------- row softmax: fp32 (n per row) -> bf16 p ----------
__global__ __launch_bounds__(256) void softmax_rows(
    const float* __restrict__ S, unsigned short* __restrict__ P, int n) {
  const int row = blockIdx.x;
  const int t = threadIdx.x;
  const float4* src = (const float4*)(S + (size_t)row * n);
  float4 v[4];
  float mx = -3.0e38f;
#pragma unroll
  for (int i = 0; i < 4; ++i) {
    v[i] = src[i * 256 + t];
    mx = fmaxf(mx, fmaxf(fmaxf(v[i].x, v[i].y), fmaxf(v[i].z, v[i].w)));
  }
#pragma unroll
  for (int off = 32; off; off >>= 1) mx = fmaxf(mx, __shfl_xor(mx, off));
  __shared__ float redm[4], reds[4];
  const int wid = t >> 6, lane = t & 63;
  if (lane == 0) redm[wid] = mx;
  __syncthreads();
  mx = fmaxf(fmaxf(redm[0], redm[1]), fmaxf(redm[2], redm[3]));
  float sum = 0.f;
#pragma unroll
  for (int i = 0; i < 4; ++i) {
    v[i].x = __expf(v[i].x - mx);
    v[i].y = __expf(v[i].y - mx);
    v[i].z = __expf(v[i].z - mx);
    v[i].w = __expf(v[i].w - mx);
    sum += (v[i].x + v[i].y) + (v[i].z + v[i].w);
  }
#pragma unroll
  for (int off = 32; off; off >>= 1) sum += __shfl_xor(sum, off);
  if (lane == 0) reds[wid] = sum;
  __syncthreads();
  sum = (reds[0] + reds[1]) + (reds[2] + reds[3]);
  float inv = 1.0f / sum;
#pragma unroll
  for (int i = 0; i < 4; ++i) {
    ushort4 o;
    o.x = f2bf(v[i].x * inv);
    o.y = f2bf(v[i].y * inv);
    o.z = f2bf(v[i].z * inv);
    o.w = f2bf(v[i].w * inv);
    *(ushort4*)(P + (size_t)row * n + (size_t)(i * 256 + t) * 4) = o;
  }
}

// ---------- launch ----------
extern "C" void kernel_launch(void* const* d_in, const int* in_sizes, int n_in,
                              void* d_out, int out_size, void* d_ws, size_t ws_size,
                              hipStream_t stream) {
  (void)in_sizes; (void)n_in; (void)out_size; (void)ws_size;
  const float* x  = (const float*)d_in[0];
  const float* Wq = (const float*)d_in[1];
  const float* Wk = (const float*)d_in[2];
  const float* Wv = (const float*)d_in[3];
  const int N = 4096, D = 1024;
  const size_t MB = 1ull << 20;
  const unsigned MEL = (unsigned)(MB / 2);   // bf16 elements per MB
  char* ws = (char*)d_ws;
  // liveness-phased layout (peak 184 MB):
  unsigned short* xh  = (unsigned short*)(ws + 0 * MB);    // live all phases
  unsigned short* xl  = (unsigned short*)(ws + 8 * MB);
  unsigned short* wqh = (unsigned short*)(ws + 16 * MB);   // dead after M
  unsigned short* wql = (unsigned short*)(ws + 24 * MB);
  unsigned short* wkh = (unsigned short*)(ws + 32 * MB);   // dead after M
  unsigned short* wkl = (unsigned short*)(ws + 40 * MB);
  unsigned short* wvh = (unsigned short*)(ws + 48 * MB);   // live till out GEMM
  unsigned short* Mth = (unsigned short*)(ws + 56 * MB);   // 2 MB
  unsigned short* Mtl = (unsigned short*)(ws + 58 * MB);   // 2 MB
  unsigned short* p   = (unsigned short*)(ws + 64 * MB);   // 32 MB (after softmax)
  float*          Mpart = (float*)(ws + 96 * MB);          // 16 x 4 MB
  float*          ypart = (float*)(ws + 96 * MB);          // 4 x 16 MB (over Mpart)
  float*          zpart = (float*)(ws + 96 * MB);          // 4 x 16 MB (over ypart)
  unsigned short* yh  = (unsigned short*)(ws + 16 * MB);   // over wqh (after M)
  unsigned short* yl  = (unsigned short*)(ws + 24 * MB);   // over wql
  unsigned short* zh  = (unsigned short*)(ws + 32 * MB);   // over wkh (after M)
  unsigned short* zl  = (unsigned short*)(ws + 40 * MB);   // over wkl
  unsigned short* xTh = (unsigned short*)(ws + 160 * MB);  // 8 MB
  unsigned short* xTl = (unsigned short*)(ws + 168 * MB);  // 8 MB (scratch)
  unsigned short* wvl = (unsigned short*)(ws + 176 * MB);  // 8 MB (scratch)
  float* score = (float*)d_out;
  float* out   = (float*)d_out;

  // 1) splits
  split_plain<<<4096, 256, 0, stream>>>((const float4*)x,  (ushort4*)xh,  (ushort4*)xl,  1048576);
  split_plain<<<4096, 256, 0, stream>>>((const float4*)Wq, (ushort4*)wqh, (ushort4*)wql, 1048576);
  split_plain<<<4096, 256, 0, stream>>>((const float4*)Wk, (ushort4*)wkh, (ushort4*)wkl, 1048576);
  split_T<<<dim3(N / 32, D / 32), 256, 0, stream>>>(Wv, wvh, wvl, D, N);   // wvh = Wv^T
  split_T<<<dim3(D / 32, N / 32), 256, 0, stream>>>(x, xTh, xTl, N, D);    // xTh = x^T (1024x4096)

  // 2) M = Wq @ Wk^T (1024x1024, K=4096), 3-pass split, 16-way K-split (256 wg)
  gemm_fused3<false><<<dim3(16, 16), 512, 0, stream>>>(
      wqh, 0u, 8 * MEL, 16 * MEL, 24 * MEL,
      1024, 4096, 256, 4, Mpart, (size_t)1024 * 1024);
  // 3) Mt = transpose(sum Mpart) -> split hi/lo bf16
  reduceT_M<<<dim3(32, 32), 256, 0, stream>>>(Mpart, Mth, Mtl, 16);

  // 4) y = x @ Mt^T (4096x1024, K=1024), 3-pass split, 4-way K-split (256 wg)
  //    [r14 FIX vs r13: Bh/Bl = Mth/Mtl at +56/+58 MB, not 40/42]
  gemm_fused3<false><<<dim3(64, 4), 512, 0, stream>>>(
      xh, 0u, 8 * MEL, 56 * MEL, 58 * MEL,
      1024, 1024, 256, 4, ypart, (size_t)4096 * 1024);
  // 5) yh/yl = split(sum ypart)  (over dead wq region)
  reduce_split<<<4096, 256, 0, stream>>>(
      (const float4*)ypart, (ushort4*)yh, (ushort4*)yl, 1048576, 4, 1048576);

  // 6) score = y @ x^T (4096x4096, K=1024), 3-pass split -> fp32 d_out
  gemm_fused3<true><<<dim3(256, 1), 512, 0, stream>>>(
      xh, 16 * MEL, 24 * MEL, 0u, 8 * MEL,
      N, 1024, 1024, 16, score, 0);

  // 7) p = softmax(score) -> bf16
  softmax_rows<<<N, 256, 0, stream>>>(score, p, N);

  // 8) z = p @ x (4096x1024, K=4096) via B=xT; 4-way K-split (256 wg) -> fp32
  gemm_plain<0, false><<<dim3(64, 4), 512, 0, stream>>>(
      p, xTh, 1024, 4096, 1024, 4, zpart, nullptr, (size_t)4096 * 1024);
  // 9) zh/zl = split(sum zpart)  (over dead wk region)
  reduce_split<<<4096, 256, 0, stream>>>(
      (const float4*)zpart, (ushort4*)zh, (ushort4*)zl, 1048576, 4, 1048576);

  // 10) out = z @ Wv = z @ wvh^T (4096x4096, K=1024) -> fp32 d_out
  gemm_plain<0, true><<<256, 512, 0, stream>>>(
      zh, wvh, N, 1024, 1024, 16, out, nullptr, 0);
}

// Round 15
// 298.017 us; speedup vs baseline: 2.6115x; 1.1242x over previous
//
#include <hip/hip_runtime.h>
#include <hip/hip_bf16.h>
#include <stdint.h>

// ---------- helpers ----------
typedef __attribute__((ext_vector_type(8))) short short8v;    // 8 x 16-bit (4 VGPRs)
typedef __attribute__((ext_vector_type(8))) _Float16 half8v;  // 8 x f16
typedef __attribute__((ext_vector_type(4))) float f32x4;

__device__ __forceinline__ unsigned short f2bf(float f) {
  unsigned u = __builtin_bit_cast(unsigned, f);
  unsigned r = 0x7fffu + ((u >> 16) & 1u);          // round-to-nearest-even
  return (unsigned short)((u + r) >> 16);
}
__device__ __forceinline__ float bf2f(unsigned short h) {
  unsigned u = ((unsigned)h) << 16;
  return __builtin_bit_cast(float, u);
}
__device__ __forceinline__ unsigned short f2h(float f) {
  _Float16 h = (_Float16)f;                         // RTNE
  return __builtin_bit_cast(unsigned short, h);
}
__device__ __forceinline__ void gload_lds16(const void* g, void* l) {
  __builtin_amdgcn_global_load_lds(
      (const __attribute__((address_space(1))) void*)g,
      (__attribute__((address_space(3))) void*)l, 16, 0, 0);
}
#define SBAR  __builtin_amdgcn_s_barrier()
#define SCHED __builtin_amdgcn_sched_barrier(0)

// ---------- split / convert kernels ----------
__global__ __launch_bounds__(256) void split_plain(
    const float4* __restrict__ X, ushort4* __restrict__ H, ushort4* __restrict__ L, int n4) {
  int idx = blockIdx.x * 256 + threadIdx.x;
  if (idx >= n4) return;
  float4 v = X[idx];
  ushort4 h, l;
  h.x = f2bf(v.x); l.x = f2bf(v.x - bf2f(h.x));
  h.y = f2bf(v.y); l.y = f2bf(v.y - bf2f(h.y));
  h.z = f2bf(v.z); l.z = f2bf(v.z - bf2f(h.z));
  h.w = f2bf(v.w); l.w = f2bf(v.w - bf2f(h.w));
  H[idx] = h; L[idx] = l;
}

__global__ __launch_bounds__(256) void tof16_plain(
    const float4* __restrict__ X, ushort4* __restrict__ H, int n4) {
  int idx = blockIdx.x * 256 + threadIdx.x;
  if (idx >= n4) return;
  float4 v = X[idx];
  ushort4 h;
  h.x = f2h(v.x); h.y = f2h(v.y); h.z = f2h(v.z); h.w = f2h(v.w);
  H[idx] = h;
}

__global__ __launch_bounds__(256) void split_T(
    const float* __restrict__ W, unsigned short* __restrict__ H,
    unsigned short* __restrict__ L, int Kd, int Nd) {
  __shared__ float tile[32][33];
  const int t = threadIdx.x;
  const int c = t & 31;
  const int r0 = t >> 5;
  const int k0 = blockIdx.y * 32, n0 = blockIdx.x * 32;
#pragma unroll
  for (int i = 0; i < 4; ++i) {
    int r = r0 + i * 8;
    tile[r][c] = W[(size_t)(k0 + r) * Nd + n0 + c];
  }
  __syncthreads();
#pragma unroll
  for (int i = 0; i < 4; ++i) {
    int n = r0 + i * 8;
    float f = tile[c][n];
    unsigned short h = f2bf(f);
    unsigned short l = f2bf(f - bf2f(h));
    size_t o = (size_t)(n0 + n) * Kd + k0 + c;
    H[o] = h; L[o] = l;
  }
}

// ---------- M-transpose reduce: Mt[b][a] = split(sum_s Mpart[s][a][b]) ----------
__global__ __launch_bounds__(256) void reduceT_M(
    const float* __restrict__ P, unsigned short* __restrict__ H,
    unsigned short* __restrict__ L, int nsplit) {
  __shared__ float tile[32][33];
  const int t = threadIdx.x;
  const int c = t & 31;
  const int r0 = t >> 5;
  const int a0 = blockIdx.y * 32, b0 = blockIdx.x * 32;
#pragma unroll
  for (int i = 0; i < 4; ++i) {
    int r = r0 + i * 8;
    float s = 0.f;
    for (int sp = 0; sp < nsplit; ++sp)
      s += P[(size_t)sp * 1048576 + (size_t)(a0 + r) * 1024 + b0 + c];
    tile[r][c] = s;
  }
  __syncthreads();
#pragma unroll
  for (int i = 0; i < 4; ++i) {
    int b = r0 + i * 8;
    float f = tile[c][b];                 // = M[a0+c][b0+b]
    unsigned short h = f2bf(f);
    size_t o = (size_t)(b0 + b) * 1024 + a0 + c;   // Mt[b][a]
    H[o] = h;
    L[o] = f2bf(f - bf2f(h));
  }
}

// ---------- reduce+split (bf16 hi/lo): H/L = split(sum_s P[s]) ----------
__global__ __launch_bounds__(256) void reduce_split(
    const float4* __restrict__ P, ushort4* __restrict__ H, ushort4* __restrict__ L,
    int n4, int nsplit, int stride4) {
  int idx = blockIdx.x * 256 + threadIdx.x;
  if (idx >= n4) return;
  float4 s = P[idx];
  for (int sp = 1; sp < nsplit; ++sp) {
    float4 v = P[(size_t)sp * stride4 + idx];
    s.x += v.x; s.y += v.y; s.z += v.z; s.w += v.w;
  }
  ushort4 h, l;
  h.x = f2bf(s.x); l.x = f2bf(s.x - bf2f(h.x));
  h.y = f2bf(s.y); l.y = f2bf(s.y - bf2f(h.y));
  h.z = f2bf(s.z); l.z = f2bf(s.z - bf2f(h.z));
  h.w = f2bf(s.w); l.w = f2bf(s.w - bf2f(h.w));
  H[idx] = h; L[idx] = l;
}

// ---------- reduce -> f16: H = f16(sum_s P[s]) ----------
__global__ __launch_bounds__(256) void reduce_f16(
    const float4* __restrict__ P, ushort4* __restrict__ H,
    int n4, int nsplit, int stride4) {
  int idx = blockIdx.x * 256 + threadIdx.x;
  if (idx >= n4) return;
  float4 s = P[idx];
  for (int sp = 1; sp < nsplit; ++sp) {
    float4 v = P[(size_t)sp * stride4 + idx];
    s.x += v.x; s.y += v.y; s.z += v.z; s.w += v.w;
  }
  ushort4 h;
  h.x = f2h(s.x); h.y = f2h(s.y); h.z = f2h(s.z); h.w = f2h(s.w);
  H[idx] = h;
}

// ---------- FUSED split GEMM (r9-proven body): C = Ah@Bl^T + Ah@Bh^T + Al@Bh^T ----------
// One base pointer + uniform element offsets. 256x256 tile, BK=32, 2-slot ring.
// Sync skeleton tripwire-proven (r6-r14): each sub-block {vmcnt(N); SBAR; reads;
// stage(t+1); MFMA}; stage FIFO [Ah,Bl,Bh,Al]; vmcnt 4/6/6 steady, 4/2/0 tail.
// K-split via blockIdx.y (koff, partStride), tilesX mapping when !SWZ. fp32 C.
template<bool SWZ>
__global__ __launch_bounds__(512, 1) void gemm_fused3(
    const unsigned short* __restrict__ base,
    unsigned dAh, unsigned dAl, unsigned dBh, unsigned dBl,
    int N, int K, int kchunk, int tilesX,
    float* __restrict__ Cf, size_t partStride) {
  __shared__ unsigned short lds[65536];   // 2 slots x [Ah|Bh|Bl|Al] x 8192 ush
  const int AH = 0, BH = 8192, BL = 16384, AL = 24576;
  const int NT = kchunk >> 5;
  const int wg = blockIdx.x;
  int bx, by;
  if (SWZ) { const int sw = ((wg & 7) << 5) | (wg >> 3); bx = sw & 15; by = sw >> 4; }
  else     { bx = wg % tilesX; by = wg / tilesX; }
  const int m0 = by << 8, n0 = bx << 8;
  const unsigned koff = (unsigned)blockIdx.y * (unsigned)kchunk;
  Cf += (size_t)blockIdx.y * partStride;

  const int tid = threadIdx.x;
  const int w = tid >> 6, lane = tid & 63;
  const int wr = w >> 2, wc = w & 3;               // wave tile 128x64
  const int lr = lane & 15;
  const int phys = (lane >> 4) ^ ((lr >> 1) & 3);  // read-side swizzle
  const int aoff = (wr * 128 + lr) * 32 + phys * 8;   // + m*512
  const int boff = (wc * 64 + lr) * 32 + phys * 8;    // + n*512
  const int rst = tid >> 2;                            // staging source row
  const int ssrc = ((tid & 3) ^ ((tid >> 3) & 3)) * 8; // inverse-swizzled k-slot
  const unsigned jstep = 128u * (unsigned)K;

  const unsigned voffA = (unsigned)(m0 + rst) * (unsigned)K + (unsigned)ssrc + koff;
  const unsigned voffB = (unsigned)(n0 + rst) * (unsigned)K + (unsigned)ssrc + koff;

  f32x4 acc[8][4];
#pragma unroll
  for (int m = 0; m < 8; ++m)
#pragma unroll
    for (int n = 0; n < 4; ++n) acc[m][n] = {0.f, 0.f, 0.f, 0.f};

#define STG2(dsel, vo, loff, s, tt) do {                                     \
    const unsigned o_ = (vo) + (dsel) + (unsigned)(tt) * 32u;                \
    gload_lds16(base + o_,         &lds[(s) + (loff) + (w << 9)]);           \
    gload_lds16(base + o_ + jstep, &lds[(s) + (loff) + 4096 + (w << 9)]);    \
  } while (0)

  // prologue: stage tile 0 into slot 0, FIFO order [Ah, Bl, Bh, Al]  (8 ops)
  STG2(dAh, voffA, AH, 0, 0);
  STG2(dBl, voffB, BL, 0, 0);
  STG2(dBh, voffB, BH, 0, 0);
  STG2(dAl, voffA, AL, 0, 0);

  for (int t = 0; t < NT; ++t) {
    const int slot = (t & 1) << 15;
    const int slot1 = ((t + 1) & 1) << 15;
    const bool st = (t + 1) < NT;
    short8v ahf[8];                          // live across blocks 1-2
    // ---- block1 (h,l): certify Ah(t),Bl(t); outstanding 8 -> vmcnt(4) ----
    SCHED; asm volatile("s_waitcnt vmcnt(4)"); SBAR; SCHED;
    {
      short8v bf[4];
#pragma unroll
      for (int n = 0; n < 4; ++n)
        bf[n] = *(const short8v*)&lds[slot + BL + boff + n * 512];
#pragma unroll
      for (int m = 0; m < 8; ++m)
        ahf[m] = *(const short8v*)&lds[slot + AH + aoff + m * 512];
      if (st) { STG2(dAh, voffA, AH, slot1, t + 1); STG2(dBl, voffB, BL, slot1, t + 1); }
      __builtin_amdgcn_s_setprio(1);
#pragma unroll
      for (int m = 0; m < 8; ++m)
#pragma unroll
        for (int n = 0; n < 4; ++n)
          acc[m][n] = __builtin_amdgcn_mfma_f32_16x16x32_bf16(ahf[m], bf[n], acc[m][n], 0, 0, 0);
      __builtin_amdgcn_s_setprio(0);
    }
    // ---- block2 (h,h): certify Bh(t); vmcnt(6) steady / (2) tail ----
    SCHED;
    if (st) { asm volatile("s_waitcnt vmcnt(6)"); }
    else    { asm volatile("s_waitcnt vmcnt(2)"); }
    SBAR; SCHED;
    short8v bh[4];                           // lives through block3
    {
#pragma unroll
      for (int n = 0; n < 4; ++n)
        bh[n] = *(const short8v*)&lds[slot + BH + boff + n * 512];
      if (st) { STG2(dBh, voffB, BH, slot1, t + 1); }
      __builtin_amdgcn_s_setprio(1);
#pragma unroll
      for (int m = 0; m < 8; ++m)
#pragma unroll
        for (int n = 0; n < 4; ++n)
          acc[m][n] = __builtin_amdgcn_mfma_f32_16x16x32_bf16(ahf[m], bh[n], acc[m][n], 0, 0, 0);
      __builtin_amdgcn_s_setprio(0);
    }
    // ahf dies here
    // ---- block3 (l,h): certify Al(t); vmcnt(6) steady / (0) tail ----
    SCHED;
    if (st) { asm volatile("s_waitcnt vmcnt(6)"); }
    else    { asm volatile("s_waitcnt vmcnt(0)"); }
    SBAR; SCHED;
    {
      short8v alf[8];
#pragma unroll
      for (int m = 0; m < 8; ++m)
        alf[m] = *(const short8v*)&lds[slot + AL + aoff + m * 512];
      if (st) { STG2(dAl, voffA, AL, slot1, t + 1); }
      __builtin_amdgcn_s_setprio(1);
#pragma unroll
      for (int m = 0; m < 8; ++m)
#pragma unroll
        for (int n = 0; n < 4; ++n)
          acc[m][n] = __builtin_amdgcn_mfma_f32_16x16x32_bf16(alf[m], bh[n], acc[m][n], 0, 0, 0);
      __builtin_amdgcn_s_setprio(0);
    }
    SCHED;
    // no end-of-tile barrier: block1's SBAR of tile t+1 separates the last
    // reads of slot (t-1)&1 from the next writes to it.
  }
#undef STG2

  // epilogue: frag r -> row=(lane>>4)*4+r, col=lane&15  [m89/m91-verified]
  const int crow = m0 + wr * 128 + ((lane >> 4) << 2);
  const int ccol = n0 + wc * 64 + lr;
#pragma unroll
  for (int mi = 0; mi < 8; ++mi)
#pragma unroll
    for (int r = 0; r < 4; ++r) {
      const int row = crow + mi * 16 + r;
#pragma unroll
      for (int n = 0; n < 4; ++n)
        Cf[(size_t)row * N + ccol + n * 16] = acc[mi][n][r];
    }
}

// ---------- plain single-pass GEMM (r9-proven body): C = A @ B^T ----------
// 4-deep ring, counted vmcnt 8/4/0 before the barrier, one SBAR per tile.
// SWZ flag, K-split via blockIdx.y (kchunk, partStride), tilesX.
// DT 0: bf16 MFMA; 1: f16 MFMA (same fragment/C-D layout, m121/m123).
// EPI 0: fp32; 1: bf16.
template<int EPI, bool SWZ, int DT>
__global__ __launch_bounds__(512, 2) void gemm_plain(
    const unsigned short* __restrict__ A, const unsigned short* __restrict__ B,
    int N, int K, int kchunk, int tilesX,
    float* __restrict__ Cf, unsigned short* __restrict__ Ch, size_t partStride) {
  __shared__ unsigned short lds[65536];   // 4 slots x (A 8192 + B 8192)
  const int NT = kchunk >> 5;
  const int wg = blockIdx.x;
  int bx, by;
  if (SWZ) { const int sw = ((wg & 7) << 5) | (wg >> 3); bx = sw & 15; by = sw >> 4; }
  else     { bx = wg % tilesX; by = wg / tilesX; }
  const int m0 = by << 8, n0 = bx << 8;
  const unsigned koff = (unsigned)blockIdx.y * (unsigned)kchunk;
  Cf += (size_t)blockIdx.y * partStride;

  const int tid = threadIdx.x;
  const int w = tid >> 6, lane = tid & 63;
  const int wr = w >> 2, wc = w & 3;
  const int lr = lane & 15;
  const int phys = (lane >> 4) ^ ((lr >> 1) & 3);
  const int aoff = (wr * 128 + lr) * 32 + phys * 8;
  const int boff = 8192 + (wc * 64 + lr) * 32 + phys * 8;
  const int rst = w * 16 + (lane >> 2);
  const int ssrc = ((lane & 3) ^ ((lane >> 3) & 3)) * 8;

  f32x4 acc[8][4];
#pragma unroll
  for (int m = 0; m < 8; ++m)
#pragma unroll
    for (int n = 0; n < 4; ++n) acc[m][n] = {0.f, 0.f, 0.f, 0.f};

  const unsigned short* gA = A + (size_t)(m0 + rst) * K + ssrc + koff;
  const unsigned short* gB = B + (size_t)(n0 + rst) * K + ssrc + koff;
  const size_t jstep = (size_t)128 * K;

#define MFMA_DT(af, bf, c) (DT == 1 ? \
    __builtin_amdgcn_mfma_f32_16x16x32_f16(__builtin_bit_cast(half8v, af), \
        __builtin_bit_cast(half8v, bf), (c), 0, 0, 0) : \
    __builtin_amdgcn_mfma_f32_16x16x32_bf16((af), (bf), (c), 0, 0, 0))

  // prologue: stage tiles 0..2 into slots 0..2
#pragma unroll
  for (int tau = 0; tau < 3; ++tau) {
    const int so = tau * 16384 + (w << 9);
    gload_lds16(gA + (size_t)tau * 32, &lds[so]);
    gload_lds16(gA + (size_t)tau * 32 + jstep, &lds[so + 4096]);
    gload_lds16(gB + (size_t)tau * 32, &lds[so + 8192]);
    gload_lds16(gB + (size_t)tau * 32 + jstep, &lds[so + 12288]);
  }
  asm volatile("s_waitcnt vmcnt(8)");
  SCHED; SBAR; SCHED;

  for (int t = 0; t < NT; ++t) {
    const int sb = (t & 3) * 16384;
    if (t + 3 < NT) {
      const int so = ((t + 3) & 3) * 16384 + (w << 9);
      const unsigned short* srcA = gA + (size_t)(t + 3) * 32;
      const unsigned short* srcB = gB + (size_t)(t + 3) * 32;
      gload_lds16(srcA, &lds[so]);
      gload_lds16(srcA + jstep, &lds[so + 4096]);
      gload_lds16(srcB, &lds[so + 8192]);
      gload_lds16(srcB + jstep, &lds[so + 12288]);
    }
    short8v bfr[4], af0[4], af1[4];
#pragma unroll
    for (int n = 0; n < 4; ++n)
      bfr[n] = *(const short8v*)&lds[sb + boff + n * 512];
#pragma unroll
    for (int m = 0; m < 4; ++m)
      af0[m] = *(const short8v*)&lds[sb + aoff + m * 512];
#pragma unroll
    for (int m = 0; m < 4; ++m)
      af1[m] = *(const short8v*)&lds[sb + aoff + 2048 + m * 512];
    __builtin_amdgcn_s_setprio(1);
#pragma unroll
    for (int m = 0; m < 4; ++m)
#pragma unroll
      for (int n = 0; n < 4; ++n)
        acc[m][n] = MFMA_DT(af0[m], bfr[n], acc[m][n]);
#pragma unroll
    for (int m = 0; m < 4; ++m)
#pragma unroll
      for (int n = 0; n < 4; ++n)
        acc[4 + m][n] = MFMA_DT(af1[m], bfr[n], acc[4 + m][n]);
    __builtin_amdgcn_s_setprio(0);
    SCHED;
    if (t < NT - 3)       { asm volatile("s_waitcnt vmcnt(8)"); }
    else if (t == NT - 3) { asm volatile("s_waitcnt vmcnt(4)"); }
    else if (t == NT - 2) { asm volatile("s_waitcnt vmcnt(0)"); }
    SCHED;
    if (t < NT - 1) { SBAR; SCHED; }
  }
#undef MFMA_DT

  const int crow = m0 + wr * 128 + ((lane >> 4) << 2);
  const int ccol = n0 + wc * 64 + lr;
#pragma unroll
  for (int mi = 0; mi < 8; ++mi)
#pragma unroll
    for (int r = 0; r < 4; ++r) {
      const int row = crow + mi * 16 + r;
#pragma unroll
      for (int n = 0; n < 4; ++n) {
        const int col = ccol + n * 16;
        const float f = acc[mi][n][r];
        const size_t o = (size_t)row * N + col;
        if (EPI == 0) Cf[o] = f;
        else          Ch[o] = f2bf(f);
      }
    }
}

// ---------- row softmax: fp32 (n per row) -> bf16 p ----------
__global__ __launch_bounds__(256) void softmax_rows(
    const float* __restrict__ S, unsigned short* __restrict__ P, int n) {
  const int row = blockIdx.x;
  const int t = threadIdx.x;
  const float4* src = (const float4*)(S + (size_t)row * n);
  float4 v[4];
  float mx = -3.0e38f;
#pragma unroll
  for (int i = 0; i < 4; ++i) {
    v[i] = src[i * 256 + t];
    mx = fmaxf(mx, fmaxf(fmaxf(v[i].x, v[i].y), fmaxf(v[i].z, v[i].w)));
  }
#pragma unroll
  for (int off = 32; off; off >>= 1) mx = fmaxf(mx, __shfl_xor(mx, off));
  __shared__ float redm[4], reds[4];
  const int wid = t >> 6, lane = t & 63;
  if (lane == 0) redm[wid] = mx;
  __syncthreads();
  mx = fmaxf(fmaxf(redm[0], redm[1]), fmaxf(redm[2], redm[3]));
  float sum = 0.f;
#pragma unroll
  for (int i = 0; i < 4; ++i) {
    v[i].x = __expf(v[i].x - mx);
    v[i].y = __expf(v[i].y - mx);
    v[i].z = __expf(v[i].z - mx);
    v[i].w = __expf(v[i].w - mx);
    sum += (v[i].x + v[i].y) + (v[i].z + v[i].w);
  }
#pragma unroll
  for (int off = 32; off; off >>= 1) sum += __shfl_xor(sum, off);
  if (lane == 0) reds[wid] = sum;
  __syncthreads();
  sum = (reds[0] + reds[1]) + (reds[2] + reds[3]);
  float inv = 1.0f / sum;
#pragma unroll
  for (int i = 0; i < 4; ++i) {
    ushort4 o;
    o.x = f2bf(v[i].x * inv);
    o.y = f2bf(v[i].y * inv);
    o.z = f2bf(v[i].z * inv);
    o.w = f2bf(v[i].w * inv);
    *(ushort4*)(P + (size_t)row * n + (size_t)(i * 256 + t) * 4) = o;
  }
}

// ---------- launch ----------
extern "C" void kernel_launch(void* const* d_in, const int* in_sizes, int n_in,
                              void* d_out, int out_size, void* d_ws, size_t ws_size,
                              hipStream_t stream) {
  (void)in_sizes; (void)n_in; (void)out_size; (void)ws_size;
  const float* x  = (const float*)d_in[0];
  const float* Wq = (const float*)d_in[1];
  const float* Wk = (const float*)d_in[2];
  const float* Wv = (const float*)d_in[3];
  const int N = 4096, D = 1024;
  const size_t MB = 1ull << 20;
  const unsigned MEL = (unsigned)(MB / 2);   // 16-bit elements per MB
  char* ws = (char*)d_ws;
  // liveness-phased layout (peak 192 MB):
  unsigned short* xh  = (unsigned short*)(ws + 0 * MB);    // live all phases
  unsigned short* xl  = (unsigned short*)(ws + 8 * MB);
  unsigned short* wqh = (unsigned short*)(ws + 16 * MB);   // dead after M
  unsigned short* wql = (unsigned short*)(ws + 24 * MB);
  unsigned short* wkh = (unsigned short*)(ws + 32 * MB);   // dead after M
  unsigned short* wkl = (unsigned short*)(ws + 40 * MB);
  unsigned short* wvh = (unsigned short*)(ws + 48 * MB);   // live till out GEMM
  unsigned short* Mth = (unsigned short*)(ws + 56 * MB);   // 2 MB
  unsigned short* Mtl = (unsigned short*)(ws + 58 * MB);   // 2 MB
  unsigned short* p   = (unsigned short*)(ws + 64 * MB);   // 32 MB (after softmax)
  float*          Mpart = (float*)(ws + 96 * MB);          // 16 x 4 MB
  float*          ypart = (float*)(ws + 96 * MB);          // 4 x 16 MB (over Mpart)
  float*          zpart = (float*)(ws + 96 * MB);          // 4 x 16 MB (over ypart)
  unsigned short* y16 = (unsigned short*)(ws + 16 * MB);   // over wqh (after M)
  unsigned short* zh  = (unsigned short*)(ws + 32 * MB);   // over wkh (after M)
  unsigned short* zl  = (unsigned short*)(ws + 40 * MB);   // over wkl
  unsigned short* xTh = (unsigned short*)(ws + 160 * MB);  // 8 MB
  unsigned short* xTl = (unsigned short*)(ws + 168 * MB);  // 8 MB (scratch)
  unsigned short* wvl = (unsigned short*)(ws + 176 * MB);  // 8 MB (scratch)
  unsigned short* x16 = (unsigned short*)(ws + 184 * MB);  // 8 MB (f16 x, plain)
  float* score = (float*)d_out;
  float* out   = (float*)d_out;

  // 1) splits / converts
  split_plain<<<4096, 256, 0, stream>>>((const float4*)x,  (ushort4*)xh,  (ushort4*)xl,  1048576);
  split_plain<<<4096, 256, 0, stream>>>((const float4*)Wq, (ushort4*)wqh, (ushort4*)wql, 1048576);
  split_plain<<<4096, 256, 0, stream>>>((const float4*)Wk, (ushort4*)wkh, (ushort4*)wkl, 1048576);
  split_T<<<dim3(N / 32, D / 32), 256, 0, stream>>>(Wv, wvh, wvl, D, N);   // wvh = Wv^T
  split_T<<<dim3(D / 32, N / 32), 256, 0, stream>>>(x, xTh, xTl, N, D);    // xTh = x^T (1024x4096)
  tof16_plain<<<4096, 256, 0, stream>>>((const float4*)x, (ushort4*)x16, 1048576);

  // 2) M = Wq @ Wk^T (1024x1024, K=4096), 3-pass split, 16-way K-split (256 wg)
  gemm_fused3<false><<<dim3(16, 16), 512, 0, stream>>>(
      wqh, 0u, 8 * MEL, 16 * MEL, 24 * MEL,
      1024, 4096, 256, 4, Mpart, (size_t)1024 * 1024);
  // 3) Mt = transpose(sum Mpart) -> split hi/lo bf16
  reduceT_M<<<dim3(32, 32), 256, 0, stream>>>(Mpart, Mth, Mtl, 16);

  // 4) y = x @ Mt^T (4096x1024, K=1024), 3-pass split, 4-way K-split (256 wg)
  gemm_fused3<false><<<dim3(64, 4), 512, 0, stream>>>(
      xh, 0u, 8 * MEL, 56 * MEL, 58 * MEL,
      1024, 1024, 256, 4, ypart, (size_t)4096 * 1024);
  // 5) y16 = f16(sum ypart)  (over dead wq region)
  reduce_f16<<<4096, 256, 0, stream>>>(
      (const float4*)ypart, (ushort4*)y16, 1048576, 4, 1048576);

  // 6) score = y16 @ x16^T (4096x4096, K=1024), SINGLE f16 pass -> fp32 d_out
  gemm_plain<0, true, 1><<<dim3(256, 1), 512, 0, stream>>>(
      y16, x16, N, 1024, 1024, 16, score, nullptr, 0);

  // 7) p = softmax(score) -> bf16
  softmax_rows<<<N, 256, 0, stream>>>(score, p, N);

  // 8) z = p @ x (4096x1024, K=4096) via B=xT; 4-way K-split (256 wg) -> fp32
  gemm_plain<0, false, 0><<<dim3(64, 4), 512, 0, stream>>>(
      p, xTh, 1024, 4096, 1024, 4, zpart, nullptr, (size_t)4096 * 1024);
  // 9) zh/zl = split(sum zpart)  (over dead wk region)
  reduce_split<<<4096, 256, 0, stream>>>(
      (const float4*)zpart, (ushort4*)zh, (ushort4*)zl, 1048576, 4, 1048576);

  // 10) out = z @ Wv = z @ wvh^T (4096x4096, K=1024) -> fp32 d_out
  gemm_plain<0, true, 0><<<256, 512, 0, stream>>>(
      zh, wvh, N, 1024, 1024, 16, out, nullptr, 0);
}